// Round 9
// baseline (402.110 us; speedup 1.0000x reference)
//
#include <hip/hip_runtime.h>

#define Bsz 1024
#define Tt  256
#define Vv  32004
#define Dd  50
#define Hh  64
#define MB  128  // vocab rows per build_tables block

typedef __bf16 b16x8 __attribute__((ext_vector_type(8)));
typedef float  f32x4 __attribute__((ext_vector_type(4)));

// Fast activations via raw gfx950 opcodes: v_exp_f32 = 2^x, v_rcp_f32 = 1/x.
// (Verified win round 5: lstm 236 -> 190 us vs IEEE div sequences.)
__device__ __forceinline__ float fexp2(float x) {
    float r;
    asm("v_exp_f32 %0, %1" : "=v"(r) : "v"(x));
    return r;
}
__device__ __forceinline__ float frcp(float x) {
    float r;
    asm("v_rcp_f32 %0, %1" : "=v"(r) : "v"(x));
    return r;
}
__device__ __forceinline__ float fsig(float x) {
    return frcp(1.0f + fexp2(x * -1.442695041f));                // 1/(1+e^-x)
}
__device__ __forceinline__ float ftanh(float x) {
    return 2.0f * frcp(1.0f + fexp2(x * -2.885390082f)) - 1.0f;  // 2/(1+e^-2x)-1
}

// fp32 -> bf16 hi/lo split (3-term product keeps ~fp32 accuracy)
__device__ __forceinline__ void cvt_hilo(const float* x, b16x8& hi, b16x8& lo) {
#pragma unroll
    for (int e = 0; e < 8; ++e) {
        const __bf16 h = (__bf16)x[e];
        hi[e] = h;
        lo[e] = (__bf16)(x[e] - (float)h);
    }
}

// ---------------------------------------------------------------------------
// Prologue (r6 form, kept): tab[v][unit*4+gate] = emb[v,:].Wih[g,:] + bias.
// ---------------------------------------------------------------------------
__launch_bounds__(256)
__global__ void build_tables(const float* __restrict__ emb,
                             const float* __restrict__ Wih1,
                             const float* __restrict__ bih1,
                             const float* __restrict__ bhh1,
                             const float* __restrict__ Wih2,
                             const float* __restrict__ bih2,
                             const float* __restrict__ bhh2,
                             float* __restrict__ tab1,
                             float* __restrict__ tab2) {
    const int tid  = threadIdx.x;
    const int w    = tid >> 6;        // wave: unit tile 16w..16w+15
    const int lane = tid & 63;
    const int q    = lane >> 4;
    const int mn   = lane & 15;
    const int v0   = blockIdx.x * MB;

    const float* Wih = blockIdx.y ? Wih2 : Wih1;
    const float* bih = blockIdx.y ? bih2 : bih1;
    const float* bhh = blockIdx.y ? bhh2 : bhh1;
    float*       tab = blockIdx.y ? tab2 : tab1;

    __shared__ __align__(16) float wlds[256 * Dd];   // 51.2 KB, flat row-major
    __shared__ __align__(16) float elds[MB * Dd];    // 25.6 KB, flat row-major

    for (int d4 = tid; d4 < 256 * Dd / 4; d4 += 256)
        *(float4*)&wlds[4 * d4] = *(const float4*)(Wih + 4 * d4);
    {
        const int ebase = v0 * Dd;
        const int elim  = Vv * Dd - ebase;
        const int mx    = Vv * Dd - 1;
        for (int d4 = tid; d4 < MB * Dd / 4; d4 += 256) {
            const int d = 4 * d4;
            float4 v;
            if (d + 4 <= elim) {
                v = *(const float4*)(emb + ebase + d);
            } else {
                v.x = emb[min(ebase + d,     mx)];
                v.y = emb[min(ebase + d + 1, mx)];
                v.z = emb[min(ebase + d + 2, mx)];
                v.w = emb[min(ebase + d + 3, mx)];
            }
            *(float4*)&elds[d] = v;
        }
    }
    __syncthreads();

    b16x8 bh[4][2], bl[4][2];
    f32x4 bias4;
#pragma unroll
    for (int k = 0; k < 4; ++k) {
        const int g = 64 * k + 16 * w + mn;
        const int base = g * Dd;
        float x[8];
#pragma unroll
        for (int j = 0; j < 8; ++j) x[j] = wlds[base + 8 * q + j];
        cvt_hilo(x, bh[k][0], bl[k][0]);
#pragma unroll
        for (int j = 0; j < 8; ++j) {
            const int col = 32 + 8 * q + j;
            x[j] = (col < Dd) ? wlds[base + col] : 0.0f;
        }
        cvt_hilo(x, bh[k][1], bl[k][1]);
        bias4[k] = bih[g] + bhh[g];
    }

#pragma unroll 1
    for (int m = 0; m < MB / 16; ++m) {
        const int base = (16 * m + mn) * Dd;
        b16x8 ah[2], al[2];
        float x[8];
#pragma unroll
        for (int j = 0; j < 8; ++j) x[j] = elds[base + 8 * q + j];
        cvt_hilo(x, ah[0], al[0]);
#pragma unroll
        for (int j = 0; j < 8; ++j) {
            const int col = 32 + 8 * q + j;
            x[j] = (col < Dd) ? elds[base + col] : 0.0f;
        }
        cvt_hilo(x, ah[1], al[1]);

        f32x4 acc[4];
#pragma unroll
        for (int k = 0; k < 4; ++k) {
            f32x4 a = {0.0f, 0.0f, 0.0f, 0.0f};
#pragma unroll
            for (int kh = 0; kh < 2; ++kh) {
                a = __builtin_amdgcn_mfma_f32_16x16x32_bf16(ah[kh], bh[k][kh], a, 0, 0, 0);
                a = __builtin_amdgcn_mfma_f32_16x16x32_bf16(ah[kh], bl[k][kh], a, 0, 0, 0);
                a = __builtin_amdgcn_mfma_f32_16x16x32_bf16(al[kh], bh[k][kh], a, 0, 0, 0);
            }
            acc[k] = a;
        }
#pragma unroll
        for (int r = 0; r < 4; ++r) {
            const int vr = v0 + 16 * m + 4 * q + r;
            if (vr < Vv) {
                f32x4 o;
                o[0] = acc[0][r] + bias4[0];
                o[1] = acc[1][r] + bias4[1];
                o[2] = acc[2][r] + bias4[2];
                o[3] = acc[3][r] + bias4[3];
                *(f32x4*)(tab + (size_t)vr * 256 + (16 * w + mn) * 4) = o;
            }
        }
    }
}

// ---------------------------------------------------------------------------
// v9 recurrence: WAVE-SOLO, ZERO barriers in the 512-step loop.
// Wall time of a serial recurrence = 512 x step latency -- occupancy and
// co-residency change nothing (v3 lesson). The cross-wave h-exchange
// (write->drain->s_barrier->read, ~300 cyc) existed only because units were
// split across 4 waves. Now ONE WAVE owns ONE batch row and ALL 64 units:
// 32 MFMAs/step (16 m-tiles x 2 K-halves; 4x redundant but on the wave's own
// matrix pipe, 16%-utilized before), B = own h[64] broadcast-duplicated to
// all 16 columns. h hand-off is intra-wave: ds_write -> in-order DS pipe ->
// ds_read. Lane (q,mn) owns unit 16*(mn&3)+4q+(mn>>2); extraction = element
// pick (mn>>2) from tile (mn&3), 11 cndmask/gate. S-loads: whole wave reads
// one tab row = perfectly coalesced. 1024 waves = 1/SIMD machine-wide.
// ---------------------------------------------------------------------------
__launch_bounds__(256, 1)
__global__ void lstm_main(const int*   __restrict__ s1,
                          const int*   __restrict__ s2,
                          const int*   __restrict__ len1,
                          const int*   __restrict__ len2,
                          const float* __restrict__ tab1,
                          const float* __restrict__ tab2,
                          const float* __restrict__ Whh1,
                          const float* __restrict__ Whh2,
                          const float* __restrict__ Wl1,
                          const float* __restrict__ bl1,
                          const float* __restrict__ Wl2,
                          const float* __restrict__ bl2,
                          float* __restrict__ out) {
    const int tid  = threadIdx.x;
    const int w    = tid >> 6;        // wave id == local batch row
    const int lane = tid & 63;
    const int q    = lane >> 4;       // MFMA quad
    const int mn   = lane & 15;       // B/C column (all duplicated)
    const bool sr0 = mn & 1;          // s (tile) select bits
    const bool sr1 = (mn >> 1) & 1;
    const bool sb0 = (mn >> 2) & 1;   // r (element) select bits
    const bool sb1 = (mn >> 3) & 1;
    const int u_own = 16 * (mn & 3) + 4 * q + (mn >> 2);  // lane's hidden unit
    const int rowg  = blockIdx.x * 4 + w;                 // global batch row

    __shared__ __align__(16) __bf16 hrow[4][80];   // per-wave h, 160B stride
    __shared__ __align__(16) int toklds[4][Tt + 8];
    __shared__ float h2s[4][64];
    __shared__ float ys[4][128];

    float c = 0.0f, selh = 0.0f, selc = 0.0f;
    const f32x4 zero4 = {0.0f, 0.0f, 0.0f, 0.0f};

    for (int phase = 0; phase < 2; ++phase) {
        const float* tab  = phase ? tab2 : tab1;
        const float* Whh  = phase ? Whh2 : Whh1;
        const int*   sent = phase ? s2 : s1;
        const int*   lenp = phase ? len2 : len1;

        // barrier BEFORE re-staging: waves drift freely inside the step loop,
        // so phase-1 staging must not clobber toklds while others still read.
        __syncthreads();
        for (int i = tid; i < 4 * Tt; i += 256)
            toklds[i >> 8][i & 255] = sent[(size_t)(blockIdx.x * 4 + (i >> 8)) * Tt + (i & 255)];

        // A fragments: ALL 16 m-tiles (gate g, unit sub-tile s).
        // A[m=mn][k=8q+j] = Whh[64g+16s+mn][kh*32+8q+j].  128 VGPRs.
        b16x8 af[4][4][2];
#pragma unroll
        for (int g = 0; g < 4; ++g)
#pragma unroll
            for (int s = 0; s < 4; ++s) {
                const int gate = 64 * g + 16 * s + mn;
#pragma unroll
                for (int kh = 0; kh < 2; ++kh) {
                    const float* ar = Whh + (size_t)gate * Hh + kh * 32 + q * 8;
                    const float4 f0 = *(const float4*)ar;
                    const float4 f1 = *(const float4*)(ar + 4);
                    b16x8 a;
                    a[0] = (__bf16)f0.x; a[1] = (__bf16)f0.y;
                    a[2] = (__bf16)f0.z; a[3] = (__bf16)f0.w;
                    a[4] = (__bf16)f1.x; a[5] = (__bf16)f1.y;
                    a[6] = (__bf16)f1.z; a[7] = (__bf16)f1.w;
                    af[g][s][kh] = a;
                }
            }

        const int mi = lenp[(size_t)rowg * Hh + u_own];

        // seed h/c (zeros phase 0, gathered state phase 1)
        const float h0f = phase ? selh : 0.0f;
        c = phase ? selc : 0.0f;
        hrow[w][u_own] = (__bf16)h0f;
        selh = 0.0f; selc = 0.0f;
        __syncthreads();

        const float* tu = tab + 4 * u_own;

        int4 tk0 = *(const int4*)&toklds[w][0];
        int4 tkA = *(const int4*)&toklds[w][4];
        int4 tkB = *(const int4*)&toklds[w][8];

        f32x4 S0, S1, S2, S3, S4, S5, S6, S7;
        S0 = *(const f32x4*)(tu + (size_t)tk0.x * 256);
        S1 = *(const f32x4*)(tu + (size_t)tk0.y * 256);
        S2 = *(const f32x4*)(tu + (size_t)tk0.z * 256);
        S3 = *(const f32x4*)(tu + (size_t)tk0.w * 256);

        // element r=(sb1,sb0) from each tile, then tile s=(sr1,sr0): 11 cnd
        auto pick = [&](const f32x4& a0, const f32x4& a1,
                        const f32x4& a2, const f32x4& a3) -> float {
            const float e0 = sb1 ? (sb0 ? a0[3] : a0[2]) : (sb0 ? a0[1] : a0[0]);
            const float e1 = sb1 ? (sb0 ? a1[3] : a1[2]) : (sb0 ? a1[1] : a1[0]);
            const float e2 = sb1 ? (sb0 ? a2[3] : a2[2]) : (sb0 ? a2[1] : a2[0]);
            const float e3 = sb1 ? (sb0 ? a3[3] : a3[2]) : (sb0 ? a3[1] : a3[0]);
            const float t01 = sr0 ? e1 : e0;
            const float t23 = sr0 ? e3 : e2;
            return sr1 ? t23 : t01;
        };

        auto step = [&](int i, f32x4& Su, f32x4& Sf, int tok, int tb) {
            // refill slot (i+4)&7: no dependence on this step's compute
            Sf = *(const f32x4*)(tu + (size_t)tok * 256);

            // own-wave h read; ordered after prev step's write by in-order DS
            const b16x8 bf0 = *(const b16x8*)&hrow[w][q * 8];
            const b16x8 bf1 = *(const b16x8*)&hrow[w][32 + q * 8];

            // 32 MFMAs, G first (tanh chain is longest)
            f32x4 aG[4], aI[4], aF[4], aO[4];
#pragma unroll
            for (int s = 0; s < 4; ++s) {
                aG[s] = __builtin_amdgcn_mfma_f32_16x16x32_bf16(af[2][s][0], bf0, zero4, 0, 0, 0);
                aG[s] = __builtin_amdgcn_mfma_f32_16x16x32_bf16(af[2][s][1], bf1, aG[s], 0, 0, 0);
            }
#pragma unroll
            for (int s = 0; s < 4; ++s) {
                aI[s] = __builtin_amdgcn_mfma_f32_16x16x32_bf16(af[0][s][0], bf0, zero4, 0, 0, 0);
                aI[s] = __builtin_amdgcn_mfma_f32_16x16x32_bf16(af[0][s][1], bf1, aI[s], 0, 0, 0);
            }
#pragma unroll
            for (int s = 0; s < 4; ++s) {
                aF[s] = __builtin_amdgcn_mfma_f32_16x16x32_bf16(af[1][s][0], bf0, zero4, 0, 0, 0);
                aF[s] = __builtin_amdgcn_mfma_f32_16x16x32_bf16(af[1][s][1], bf1, aF[s], 0, 0, 0);
            }
#pragma unroll
            for (int s = 0; s < 4; ++s) {
                aO[s] = __builtin_amdgcn_mfma_f32_16x16x32_bf16(af[3][s][0], bf0, zero4, 0, 0, 0);
                aO[s] = __builtin_amdgcn_mfma_f32_16x16x32_bf16(af[3][s][1], bf1, aO[s], 0, 0, 0);
            }

            const float gG = pick(aG[0], aG[1], aG[2], aG[3]) + Su[2];
            const float gI = pick(aI[0], aI[1], aI[2], aI[3]) + Su[0];
            const float gF = pick(aF[0], aF[1], aF[2], aF[3]) + Su[1];
            const float gO = pick(aO[0], aO[1], aO[2], aO[3]) + Su[3];

            const float gv = ftanh(gG);
            const float iv = fsig(gI);
            const float fv = fsig(gF);
            const float ov = fsig(gO);
            c = fv * c + iv * gv;
            const float hv = ov * ftanh(c);
            hrow[w][u_own] = (__bf16)hv;
            if (tb + i == mi) { selh = hv; selc = c; }
            // NO barrier: next step's reads are same-wave, DS pipe in-order.
        };

        for (int tb = 0; tb < Tt; tb += 8) {
            step(0, S0, S4, tkA.x, tb);
            step(1, S1, S5, tkA.y, tb);
            const int nb1 = min(tb + 12, Tt - 4);
            const int4 tA2 = *(const int4*)&toklds[w][nb1];
            step(2, S2, S6, tkA.z, tb);
            const int nb2 = min(tb + 16, Tt - 4);
            const int4 tB2 = *(const int4*)&toklds[w][nb2];
            step(3, S3, S7, tkA.w, tb);
            step(4, S4, S0, tkB.x, tb);
            step(5, S5, S1, tkB.y, tb);
            step(6, S6, S2, tkB.z, tb);
            step(7, S7, S3, tkB.w, tb);
            tkA = tA2; tkB = tB2;
        }
    }

    // ---------------- epilogue MLP on the 4 gathered rows -------------------
    h2s[w][u_own] = selh;
    __syncthreads();
#pragma unroll
    for (int p = 0; p < 2; ++p) {
        const int idx = tid + 256 * p;        // 512 (row, neuron) tasks
        const int rr = idx >> 7, n = idx & 127;
        float a = bl1[n];
        const float* wl = Wl1 + n * 64;
#pragma unroll 8
        for (int k = 0; k < 64; ++k) a += h2s[rr][k] * wl[k];
        ys[rr][n] = ftanh(a);
    }
    __syncthreads();
    if (tid < 16) {
        const int rr = tid >> 2, o = tid & 3;
        float a = bl2[o];
        const float* wl = Wl2 + o * 128;
#pragma unroll 8
        for (int k = 0; k < 128; ++k) a += ys[rr][k] * wl[k];
        out[(size_t)(blockIdx.x * 4 + rr) * 4 + o] = a;
    }
}

// ---------------------------------------------------------------------------
extern "C" void kernel_launch(void* const* d_in, const int* in_sizes, int n_in,
                              void* d_out, int out_size, void* d_ws, size_t ws_size,
                              hipStream_t stream) {
    const int*   s1   = (const int*)d_in[0];
    const int*   s2   = (const int*)d_in[1];
    const int*   l1   = (const int*)d_in[2];
    const int*   l2   = (const int*)d_in[3];
    // d_in[4], d_in[5] (s1_s, s2_s) unused by the reference
    const float* emb  = (const float*)d_in[6];
    const float* Wih1 = (const float*)d_in[7];
    const float* Whh1 = (const float*)d_in[8];
    const float* bih1 = (const float*)d_in[9];
    const float* bhh1 = (const float*)d_in[10];
    const float* Wih2 = (const float*)d_in[11];
    const float* Whh2 = (const float*)d_in[12];
    const float* bih2 = (const float*)d_in[13];
    const float* bhh2 = (const float*)d_in[14];
    const float* Wl1  = (const float*)d_in[15];
    const float* bl1  = (const float*)d_in[16];
    const float* Wl2  = (const float*)d_in[17];
    const float* bl2  = (const float*)d_in[18];
    float* out = (float*)d_out;

    float* tab1 = (float*)d_ws;                       // [V,256] fp32, unit-major
    float* tab2 = tab1 + (size_t)Vv * 256;            // [V,256] fp32  (65.6 MB)

    dim3 grid((Vv + MB - 1) / MB, 2);
    build_tables<<<grid, 256, 0, stream>>>(emb, Wih1, bih1, bhh1,
                                           Wih2, bih2, bhh2, tab1, tab2);
    lstm_main<<<Bsz / 4, 256, 0, stream>>>(s1, s2, l1, l2, tab1, tab2,
                                           Whh1, Whh2, Wl1, bl1, Wl2, bl2, out);
}

// Round 10
// 361.349 us; speedup vs baseline: 1.1128x; 1.1128x over previous
//
#include <hip/hip_runtime.h>

#define Bsz 1024
#define Tt  256
#define Vv  32004
#define Dd  50
#define Hh  64
#define MB  128  // vocab rows per build_tables block

typedef __bf16 b16x8 __attribute__((ext_vector_type(8)));
typedef float  f32x4 __attribute__((ext_vector_type(4)));

// barrier WITHOUT vmcnt(0) drain: LDS ordering only, in-flight global loads
// (the xw register prefetch) survive across it.
__device__ __forceinline__ void barrier_novm() {
    asm volatile("s_waitcnt lgkmcnt(0)\n\ts_barrier" ::: "memory");
}
// Fast activations via raw gfx950 opcodes (verified round 5: -46us).
__device__ __forceinline__ float fexp2(float x) {
    float r;
    asm("v_exp_f32 %0, %1" : "=v"(r) : "v"(x));
    return r;
}
__device__ __forceinline__ float frcp(float x) {
    float r;
    asm("v_rcp_f32 %0, %1" : "=v"(r) : "v"(x));
    return r;
}
// PRESCALED forms: gate pre-activations arrive already multiplied by
// -log2(e) (i,f,o) or -2*log2(e) (g) -- folded into Whh frags and tab.
__device__ __forceinline__ float fsig_p(float x)  { return frcp(1.0f + fexp2(x)); }
__device__ __forceinline__ float ftanh_p(float x) { return 2.0f * frcp(1.0f + fexp2(x)) - 1.0f; }
__device__ __forceinline__ float ftanh(float x) {
    return 2.0f * frcp(1.0f + fexp2(x * -2.885390082f)) - 1.0f;
}

// fp32 -> bf16 hi/lo split (3-term product keeps ~fp32 accuracy)
__device__ __forceinline__ void cvt_hilo(const float* x, b16x8& hi, b16x8& lo) {
#pragma unroll
    for (int e = 0; e < 8; ++e) {
        const __bf16 h = (__bf16)x[e];
        hi[e] = h;
        lo[e] = (__bf16)(x[e] - (float)h);
    }
}

// ---------------------------------------------------------------------------
// Prologue: tab[v][unit*4+gate] = (emb[v,:].Wih[g,:] + bias) * sc[gate].
// sc folds the activation input scale (see fsig_p/ftanh_p).
// ---------------------------------------------------------------------------
__launch_bounds__(256)
__global__ void build_tables(const float* __restrict__ emb,
                             const float* __restrict__ Wih1,
                             const float* __restrict__ bih1,
                             const float* __restrict__ bhh1,
                             const float* __restrict__ Wih2,
                             const float* __restrict__ bih2,
                             const float* __restrict__ bhh2,
                             float* __restrict__ tab1,
                             float* __restrict__ tab2) {
    const int tid  = threadIdx.x;
    const int w    = tid >> 6;        // wave: unit tile 16w..16w+15
    const int lane = tid & 63;
    const int q    = lane >> 4;
    const int mn   = lane & 15;
    const int v0   = blockIdx.x * MB;

    const float* Wih = blockIdx.y ? Wih2 : Wih1;
    const float* bih = blockIdx.y ? bih2 : bih1;
    const float* bhh = blockIdx.y ? bhh2 : bhh1;
    float*       tab = blockIdx.y ? tab2 : tab1;

    __shared__ __align__(16) float wlds[256 * Dd];   // 51.2 KB, flat row-major
    __shared__ __align__(16) float elds[MB * Dd];    // 25.6 KB, flat row-major

    for (int d4 = tid; d4 < 256 * Dd / 4; d4 += 256)
        *(float4*)&wlds[4 * d4] = *(const float4*)(Wih + 4 * d4);
    {
        const int ebase = v0 * Dd;
        const int elim  = Vv * Dd - ebase;
        const int mx    = Vv * Dd - 1;
        for (int d4 = tid; d4 < MB * Dd / 4; d4 += 256) {
            const int d = 4 * d4;
            float4 v;
            if (d + 4 <= elim) {
                v = *(const float4*)(emb + ebase + d);
            } else {
                v.x = emb[min(ebase + d,     mx)];
                v.y = emb[min(ebase + d + 1, mx)];
                v.z = emb[min(ebase + d + 2, mx)];
                v.w = emb[min(ebase + d + 3, mx)];
            }
            *(float4*)&elds[d] = v;
        }
    }
    __syncthreads();

    b16x8 bh[4][2], bl[4][2];
    f32x4 bias4;
#pragma unroll
    for (int k = 0; k < 4; ++k) {
        const int g = 64 * k + 16 * w + mn;
        const int base = g * Dd;
        float x[8];
#pragma unroll
        for (int j = 0; j < 8; ++j) x[j] = wlds[base + 8 * q + j];
        cvt_hilo(x, bh[k][0], bl[k][0]);
#pragma unroll
        for (int j = 0; j < 8; ++j) {
            const int col = 32 + 8 * q + j;
            x[j] = (col < Dd) ? wlds[base + col] : 0.0f;
        }
        cvt_hilo(x, bh[k][1], bl[k][1]);
        bias4[k] = bih[g] + bhh[g];
    }

    // per-gate activation input scales (i,f,g,o)
    const f32x4 scale4 = {-1.442695041f, -1.442695041f, -2.885390082f, -1.442695041f};

#pragma unroll 1
    for (int m = 0; m < MB / 16; ++m) {
        const int base = (16 * m + mn) * Dd;
        b16x8 ah[2], al[2];
        float x[8];
#pragma unroll
        for (int j = 0; j < 8; ++j) x[j] = elds[base + 8 * q + j];
        cvt_hilo(x, ah[0], al[0]);
#pragma unroll
        for (int j = 0; j < 8; ++j) {
            const int col = 32 + 8 * q + j;
            x[j] = (col < Dd) ? elds[base + col] : 0.0f;
        }
        cvt_hilo(x, ah[1], al[1]);

        f32x4 acc[4];
#pragma unroll
        for (int k = 0; k < 4; ++k) {
            f32x4 a = {0.0f, 0.0f, 0.0f, 0.0f};
#pragma unroll
            for (int kh = 0; kh < 2; ++kh) {
                a = __builtin_amdgcn_mfma_f32_16x16x32_bf16(ah[kh], bh[k][kh], a, 0, 0, 0);
                a = __builtin_amdgcn_mfma_f32_16x16x32_bf16(ah[kh], bl[k][kh], a, 0, 0, 0);
                a = __builtin_amdgcn_mfma_f32_16x16x32_bf16(al[kh], bh[k][kh], a, 0, 0, 0);
            }
            acc[k] = a;
        }
#pragma unroll
        for (int r = 0; r < 4; ++r) {
            const int vr = v0 + 16 * m + 4 * q + r;
            if (vr < Vv) {
                f32x4 o;
                o[0] = (acc[0][r] + bias4[0]) * scale4[0];
                o[1] = (acc[1][r] + bias4[1]) * scale4[1];
                o[2] = (acc[2][r] + bias4[2]) * scale4[2];
                o[3] = (acc[3][r] + bias4[3]) * scale4[3];
                *(f32x4*)(tab + (size_t)vr * 256 + (16 * w + mn) * 4) = o;
            }
        }
    }
}

// ---------------------------------------------------------------------------
// v10 recurrence: v8 structure x TWO independent batch-row groups per block.
// v9's counters calibrated the cost model: single-wave MFMA ~17 cyc, VALU and
// MFMA issue serialize in one wave -> v8 step = 131 MFMA + 348 VALU + ~310
// STALL (barrier + exposed ds_read + drains). The stall is fixed per barrier
// cadence, so amortize it: block = 8 rows (A=0..3, B=4..7), same 4 waves run
// both recurrences interleaved; one superstep = one barrier advances BOTH
// groups one token-step. af (Whh frags, prescaled) is shared. Group B's
// MFMAs/reads complete under group A's VALU chain (independent -> ILP).
// ---------------------------------------------------------------------------
__launch_bounds__(256, 1)
__global__ void lstm_main(const int*   __restrict__ s1,
                          const int*   __restrict__ s2,
                          const int*   __restrict__ len1,
                          const int*   __restrict__ len2,
                          const float* __restrict__ tab1,
                          const float* __restrict__ tab2,
                          const float* __restrict__ Whh1,
                          const float* __restrict__ Whh2,
                          const float* __restrict__ Wl1,
                          const float* __restrict__ bl1,
                          const float* __restrict__ Wl2,
                          const float* __restrict__ bl2,
                          float* __restrict__ out) {
    const int tid  = threadIdx.x;
    const int w    = tid >> 6;        // wave: unit tile [16w,16w+16)
    const int lane = tid & 63;
    const int q    = lane >> 4;       // MFMA quad
    const int mn   = lane & 15;       // B/C column
    const int rowA = mn & 3;          // group-A batch row (rows 0..3)
    const int rowB = rowA + 4;        // group-B batch row (rows 4..7)
    const bool sb0 = (mn >> 2) & 1;   // rsel bit0
    const bool sb1 = (mn >> 3) & 1;   // rsel bit1
    const int u_own = 16 * w + 4 * q + (mn >> 2);  // this lane's hidden unit
    const int b0   = blockIdx.x * 8;

    __shared__ __align__(16) __bf16 hsh[2][8][96];  // row stride 192B: 2-way banks
    __shared__ __align__(16) int toklds[8][Tt + 8]; // per-row contiguous, padded
    __shared__ float h2s[8][64];
    __shared__ float ys[8][128];

    float cA = 0.0f, selhA = 0.0f, selcA = 0.0f;
    float cB = 0.0f, selhB = 0.0f, selcB = 0.0f;
    const f32x4 zero4 = {0.0f, 0.0f, 0.0f, 0.0f};

    for (int phase = 0; phase < 2; ++phase) {
        const float* tab  = phase ? tab2 : tab1;
        const float* Whh  = phase ? Whh2 : Whh1;
        const int*   sent = phase ? s2 : s1;
        const int*   lenp = phase ? len2 : len1;

        // stage tokens per-row contiguous (8 rows; all waves synced at the
        // final in-loop barrier of the previous phase, so no clobber race)
        for (int i = tid; i < 8 * Tt; i += 256)
            toklds[i >> 8][i & 255] = sent[(size_t)(b0 + (i >> 8)) * Tt + (i & 255)];

        // A fragments, PRESCALED: m-tile k covers gates 64k+16w+0..15
        b16x8 af[8];
#pragma unroll
        for (int k = 0; k < 4; ++k) {
            const int gate = 64 * k + 16 * w + mn;
            const float sck = (k == 2) ? -2.885390082f : -1.442695041f;
#pragma unroll
            for (int kh = 0; kh < 2; ++kh) {
                const float* ar = Whh + (size_t)gate * Hh + kh * 32 + q * 8;
                const float4 f0 = *(const float4*)ar;
                const float4 f1 = *(const float4*)(ar + 4);
                b16x8 a;
                a[0] = (__bf16)(f0.x * sck); a[1] = (__bf16)(f0.y * sck);
                a[2] = (__bf16)(f0.z * sck); a[3] = (__bf16)(f0.w * sck);
                a[4] = (__bf16)(f1.x * sck); a[5] = (__bf16)(f1.y * sck);
                a[6] = (__bf16)(f1.z * sck); a[7] = (__bf16)(f1.w * sck);
                af[2 * k + kh] = a;
            }
        }

        const int miA = lenp[(size_t)(b0 + rowA) * Hh + u_own];
        const int miB = lenp[(size_t)(b0 + rowB) * Hh + u_own];

        // seed h/c (zeros phase 0, gathered state phase 1) into buffer 0
        hsh[0][rowA][u_own] = (__bf16)(phase ? selhA : 0.0f);
        hsh[0][rowB][u_own] = (__bf16)(phase ? selhB : 0.0f);
        cA = phase ? selcA : 0.0f;
        cB = phase ? selcB : 0.0f;
        selhA = 0.0f; selcA = 0.0f; selhB = 0.0f; selcB = 0.0f;
        __syncthreads();

        const float* tu = tab + 4 * u_own;

        // token register chunks per group
        int4 a0c = *(const int4*)&toklds[rowA][0];
        int4 aC1 = *(const int4*)&toklds[rowA][4];
        int4 aC2 = *(const int4*)&toklds[rowA][8];
        int4 b0c = *(const int4*)&toklds[rowB][0];
        int4 bC1 = *(const int4*)&toklds[rowB][4];
        int4 bC2 = *(const int4*)&toklds[rowB][8];

        // S slots: 8 per group, distance-4 rotation (v8 scheme)
        f32x4 SA0, SA1, SA2, SA3, SA4, SA5, SA6, SA7;
        f32x4 SB0, SB1, SB2, SB3, SB4, SB5, SB6, SB7;
        SA0 = *(const f32x4*)(tu + (size_t)a0c.x * 256);
        SA1 = *(const f32x4*)(tu + (size_t)a0c.y * 256);
        SA2 = *(const f32x4*)(tu + (size_t)a0c.z * 256);
        SA3 = *(const f32x4*)(tu + (size_t)a0c.w * 256);
        SB0 = *(const f32x4*)(tu + (size_t)b0c.x * 256);
        SB1 = *(const f32x4*)(tu + (size_t)b0c.y * 256);
        SB2 = *(const f32x4*)(tu + (size_t)b0c.z * 256);
        SB3 = *(const f32x4*)(tu + (size_t)b0c.w * 256);

        auto pick = [&](const f32x4& a) -> float {
            const float e01 = sb0 ? a[1] : a[0];
            const float e23 = sb0 ? a[3] : a[2];
            return sb1 ? e23 : e01;
        };

        // superstep i: both groups consume slot i, refill slot (i+4)&7
        auto sstep = [&](int i, f32x4& SuA, f32x4& SfA, int tokA,
                                f32x4& SuB, f32x4& SfB, int tokB, int tb) {
            // refills first: no dependence on this step's compute
            SfA = *(const f32x4*)(tu + (size_t)tokA * 256);
            SfB = *(const f32x4*)(tu + (size_t)tokB * 256);

            const int rb = i & 1, wb = rb ^ 1;
            const b16x8 bA0 = *(const b16x8*)&hsh[rb][rowA][q * 8];
            const b16x8 bA1 = *(const b16x8*)&hsh[rb][rowA][32 + q * 8];
            const b16x8 bB0 = *(const b16x8*)&hsh[rb][rowB][q * 8];
            const b16x8 bB1 = *(const b16x8*)&hsh[rb][rowB][32 + q * 8];

            // group A MFMAs (G first: longest chain), then group B (complete
            // under A's VALU)
            f32x4 aGA = __builtin_amdgcn_mfma_f32_16x16x32_bf16(af[4], bA0, zero4, 0, 0, 0);
            aGA = __builtin_amdgcn_mfma_f32_16x16x32_bf16(af[5], bA1, aGA, 0, 0, 0);
            f32x4 aIA = __builtin_amdgcn_mfma_f32_16x16x32_bf16(af[0], bA0, zero4, 0, 0, 0);
            aIA = __builtin_amdgcn_mfma_f32_16x16x32_bf16(af[1], bA1, aIA, 0, 0, 0);
            f32x4 aFA = __builtin_amdgcn_mfma_f32_16x16x32_bf16(af[2], bA0, zero4, 0, 0, 0);
            aFA = __builtin_amdgcn_mfma_f32_16x16x32_bf16(af[3], bA1, aFA, 0, 0, 0);
            f32x4 aOA = __builtin_amdgcn_mfma_f32_16x16x32_bf16(af[6], bA0, zero4, 0, 0, 0);
            aOA = __builtin_amdgcn_mfma_f32_16x16x32_bf16(af[7], bA1, aOA, 0, 0, 0);

            f32x4 aGB = __builtin_amdgcn_mfma_f32_16x16x32_bf16(af[4], bB0, zero4, 0, 0, 0);
            aGB = __builtin_amdgcn_mfma_f32_16x16x32_bf16(af[5], bB1, aGB, 0, 0, 0);
            f32x4 aIB = __builtin_amdgcn_mfma_f32_16x16x32_bf16(af[0], bB0, zero4, 0, 0, 0);
            aIB = __builtin_amdgcn_mfma_f32_16x16x32_bf16(af[1], bB1, aIB, 0, 0, 0);
            f32x4 aFB = __builtin_amdgcn_mfma_f32_16x16x32_bf16(af[2], bB0, zero4, 0, 0, 0);
            aFB = __builtin_amdgcn_mfma_f32_16x16x32_bf16(af[3], bB1, aFB, 0, 0, 0);
            f32x4 aOB = __builtin_amdgcn_mfma_f32_16x16x32_bf16(af[6], bB0, zero4, 0, 0, 0);
            aOB = __builtin_amdgcn_mfma_f32_16x16x32_bf16(af[7], bB1, aOB, 0, 0, 0);

            // ---- group A tail ----
            {
                const float gG = pick(aGA) + SuA[2];
                const float gI = pick(aIA) + SuA[0];
                const float gF = pick(aFA) + SuA[1];
                const float gO = pick(aOA) + SuA[3];
                const float gv = ftanh_p(gG);
                const float iv = fsig_p(gI);
                const float fv = fsig_p(gF);
                const float ov = fsig_p(gO);
                cA = fv * cA + iv * gv;
                const float hv = ov * ftanh(cA);
                hsh[wb][rowA][u_own] = (__bf16)hv;
                if (tb + i == miA) { selhA = hv; selcA = cA; }
            }
            // ---- group B tail ----
            {
                const float gG = pick(aGB) + SuB[2];
                const float gI = pick(aIB) + SuB[0];
                const float gF = pick(aFB) + SuB[1];
                const float gO = pick(aOB) + SuB[3];
                const float gv = ftanh_p(gG);
                const float iv = fsig_p(gI);
                const float fv = fsig_p(gF);
                const float ov = fsig_p(gO);
                cB = fv * cB + iv * gv;
                const float hv = ov * ftanh(cB);
                hsh[wb][rowB][u_own] = (__bf16)hv;
                if (tb + i == miB) { selhB = hv; selcB = cB; }
            }
            barrier_novm();   // ONE barrier advances BOTH groups one step
        };

        for (int tb = 0; tb < Tt; tb += 8) {
            sstep(0, SA0, SA4, aC1.x, SB0, SB4, bC1.x, tb);
            sstep(1, SA1, SA5, aC1.y, SB1, SB5, bC1.y, tb);
            const int nb1 = min(tb + 12, Tt - 4);
            const int4 aN1 = *(const int4*)&toklds[rowA][nb1];
            const int4 bN1 = *(const int4*)&toklds[rowB][nb1];
            sstep(2, SA2, SA6, aC1.z, SB2, SB6, bC1.z, tb);
            const int nb2 = min(tb + 16, Tt - 4);
            const int4 aN2 = *(const int4*)&toklds[rowA][nb2];
            const int4 bN2 = *(const int4*)&toklds[rowB][nb2];
            sstep(3, SA3, SA7, aC1.w, SB3, SB7, bC1.w, tb);
            sstep(4, SA4, SA0, aC2.x, SB4, SB0, bC2.x, tb);
            sstep(5, SA5, SA1, aC2.y, SB5, SB1, bC2.y, tb);
            sstep(6, SA6, SA2, aC2.z, SB6, SB2, bC2.z, tb);
            sstep(7, SA7, SA3, aC2.w, SB7, SB3, bC2.w, tb);
            aC1 = aN1; aC2 = aN2; bC1 = bN1; bC2 = bN2;
        }
    }

    // ---------------- epilogue MLP on the 8 gathered rows -------------------
    h2s[rowA][u_own] = selhA;
    h2s[rowB][u_own] = selhB;
    __syncthreads();
#pragma unroll
    for (int p = 0; p < 4; ++p) {
        const int idx = tid + 256 * p;        // 1024 (row, neuron) tasks
        const int rr = idx >> 7, n = idx & 127;
        float a = bl1[n];
        const float* wl = Wl1 + n * 64;
#pragma unroll 8
        for (int k = 0; k < 64; ++k) a += h2s[rr][k] * wl[k];
        ys[rr][n] = ftanh(a * -0.346573590f * -2.885390082f);  // == tanh(a)
    }
    __syncthreads();
    if (tid < 32) {
        const int rr = tid >> 2, o = tid & 3;
        float a = bl2[o];
        const float* wl = Wl2 + o * 128;
#pragma unroll 8
        for (int k = 0; k < 128; ++k) a += ys[rr][k] * wl[k];
        out[(size_t)(b0 + rr) * 4 + o] = a;
    }
}

// ---------------------------------------------------------------------------
extern "C" void kernel_launch(void* const* d_in, const int* in_sizes, int n_in,
                              void* d_out, int out_size, void* d_ws, size_t ws_size,
                              hipStream_t stream) {
    const int*   s1   = (const int*)d_in[0];
    const int*   s2   = (const int*)d_in[1];
    const int*   l1   = (const int*)d_in[2];
    const int*   l2   = (const int*)d_in[3];
    // d_in[4], d_in[5] (s1_s, s2_s) unused by the reference
    const float* emb  = (const float*)d_in[6];
    const float* Wih1 = (const float*)d_in[7];
    const float* Whh1 = (const float*)d_in[8];
    const float* bih1 = (const float*)d_in[9];
    const float* bhh1 = (const float*)d_in[10];
    const float* Wih2 = (const float*)d_in[11];
    const float* Whh2 = (const float*)d_in[12];
    const float* bih2 = (const float*)d_in[13];
    const float* bhh2 = (const float*)d_in[14];
    const float* Wl1  = (const float*)d_in[15];
    const float* bl1  = (const float*)d_in[16];
    const float* Wl2  = (const float*)d_in[17];
    const float* bl2  = (const float*)d_in[18];
    float* out = (float*)d_out;

    float* tab1 = (float*)d_ws;                       // [V,256] fp32, unit-major
    float* tab2 = tab1 + (size_t)Vv * 256;            // [V,256] fp32  (65.6 MB)

    dim3 grid((Vv + MB - 1) / MB, 2);
    build_tables<<<grid, 256, 0, stream>>>(emb, Wih1, bih1, bhh1,
                                           Wih2, bih2, bhh2, tab1, tab2);
    lstm_main<<<Bsz / 8, 256, 0, stream>>>(s1, s2, l1, l2, tab1, tab2,
                                           Whh1, Whh2, Wl1, bl1, Wl2, bl2, out);
}

// Round 11
// 258.024 us; speedup vs baseline: 1.5584x; 1.4004x over previous
//
#include <hip/hip_runtime.h>

#define Bsz 1024
#define Tt  256
#define Vv  32004
#define Dd  50
#define Hh  64
#define MB  128  // vocab rows per build_tables block

typedef __bf16 b16x8 __attribute__((ext_vector_type(8)));
typedef float  f32x4 __attribute__((ext_vector_type(4)));

// barrier WITHOUT vmcnt(0) drain: LDS ordering only, in-flight global loads
// (the xw register prefetch) survive across it.
__device__ __forceinline__ void barrier_novm() {
    asm volatile("s_waitcnt lgkmcnt(0)\n\ts_barrier" ::: "memory");
}
// Fast activations via raw gfx950 opcodes (verified round 5: -46us).
__device__ __forceinline__ float fexp2(float x) {
    float r;
    asm("v_exp_f32 %0, %1" : "=v"(r) : "v"(x));
    return r;
}
__device__ __forceinline__ float frcp(float x) {
    float r;
    asm("v_rcp_f32 %0, %1" : "=v"(r) : "v"(x));
    return r;
}
// PRESCALED forms: gate pre-activations arrive already multiplied by
// -log2(e) (i,f,o) or -2*log2(e) (g) -- folded into Whh frags and tab.
// (Math verified in round 10: absmax unchanged.)
__device__ __forceinline__ float fsig_p(float x)  { return frcp(1.0f + fexp2(x)); }
__device__ __forceinline__ float ftanh_p(float x) { return 2.0f * frcp(1.0f + fexp2(x)) - 1.0f; }
__device__ __forceinline__ float ftanh(float x) {
    return 2.0f * frcp(1.0f + fexp2(x * -2.885390082f)) - 1.0f;
}

// fp32 -> bf16 hi/lo split (3-term product keeps ~fp32 accuracy)
__device__ __forceinline__ void cvt_hilo(const float* x, b16x8& hi, b16x8& lo) {
#pragma unroll
    for (int e = 0; e < 8; ++e) {
        const __bf16 h = (__bf16)x[e];
        hi[e] = h;
        lo[e] = (__bf16)(x[e] - (float)h);
    }
}

// ---------------------------------------------------------------------------
// Prologue: tab[v][unit*4+gate] = (emb[v,:].Wih[g,:] + bias) * sc[gate].
// sc folds the activation input scale (see fsig_p/ftanh_p).
// ---------------------------------------------------------------------------
__launch_bounds__(256)
__global__ void build_tables(const float* __restrict__ emb,
                             const float* __restrict__ Wih1,
                             const float* __restrict__ bih1,
                             const float* __restrict__ bhh1,
                             const float* __restrict__ Wih2,
                             const float* __restrict__ bih2,
                             const float* __restrict__ bhh2,
                             float* __restrict__ tab1,
                             float* __restrict__ tab2) {
    const int tid  = threadIdx.x;
    const int w    = tid >> 6;        // wave: unit tile 16w..16w+15
    const int lane = tid & 63;
    const int q    = lane >> 4;
    const int mn   = lane & 15;
    const int v0   = blockIdx.x * MB;

    const float* Wih = blockIdx.y ? Wih2 : Wih1;
    const float* bih = blockIdx.y ? bih2 : bih1;
    const float* bhh = blockIdx.y ? bhh2 : bhh1;
    float*       tab = blockIdx.y ? tab2 : tab1;

    __shared__ __align__(16) float wlds[256 * Dd];   // 51.2 KB, flat row-major
    __shared__ __align__(16) float elds[MB * Dd];    // 25.6 KB, flat row-major

    for (int d4 = tid; d4 < 256 * Dd / 4; d4 += 256)
        *(float4*)&wlds[4 * d4] = *(const float4*)(Wih + 4 * d4);
    {
        const int ebase = v0 * Dd;
        const int elim  = Vv * Dd - ebase;
        const int mx    = Vv * Dd - 1;
        for (int d4 = tid; d4 < MB * Dd / 4; d4 += 256) {
            const int d = 4 * d4;
            float4 v;
            if (d + 4 <= elim) {
                v = *(const float4*)(emb + ebase + d);
            } else {
                v.x = emb[min(ebase + d,     mx)];
                v.y = emb[min(ebase + d + 1, mx)];
                v.z = emb[min(ebase + d + 2, mx)];
                v.w = emb[min(ebase + d + 3, mx)];
            }
            *(float4*)&elds[d] = v;
        }
    }
    __syncthreads();

    b16x8 bh[4][2], bl[4][2];
    f32x4 bias4;
#pragma unroll
    for (int k = 0; k < 4; ++k) {
        const int g = 64 * k + 16 * w + mn;
        const int base = g * Dd;
        float x[8];
#pragma unroll
        for (int j = 0; j < 8; ++j) x[j] = wlds[base + 8 * q + j];
        cvt_hilo(x, bh[k][0], bl[k][0]);
#pragma unroll
        for (int j = 0; j < 8; ++j) {
            const int col = 32 + 8 * q + j;
            x[j] = (col < Dd) ? wlds[base + col] : 0.0f;
        }
        cvt_hilo(x, bh[k][1], bl[k][1]);
        bias4[k] = bih[g] + bhh[g];
    }

    // per-gate activation input scales (i,f,g,o)
    const f32x4 scale4 = {-1.442695041f, -1.442695041f, -2.885390082f, -1.442695041f};

#pragma unroll 1
    for (int m = 0; m < MB / 16; ++m) {
        const int base = (16 * m + mn) * Dd;
        b16x8 ah[2], al[2];
        float x[8];
#pragma unroll
        for (int j = 0; j < 8; ++j) x[j] = elds[base + 8 * q + j];
        cvt_hilo(x, ah[0], al[0]);
#pragma unroll
        for (int j = 0; j < 8; ++j) {
            const int col = 32 + 8 * q + j;
            x[j] = (col < Dd) ? elds[base + col] : 0.0f;
        }
        cvt_hilo(x, ah[1], al[1]);

        f32x4 acc[4];
#pragma unroll
        for (int k = 0; k < 4; ++k) {
            f32x4 a = {0.0f, 0.0f, 0.0f, 0.0f};
#pragma unroll
            for (int kh = 0; kh < 2; ++kh) {
                a = __builtin_amdgcn_mfma_f32_16x16x32_bf16(ah[kh], bh[k][kh], a, 0, 0, 0);
                a = __builtin_amdgcn_mfma_f32_16x16x32_bf16(ah[kh], bl[k][kh], a, 0, 0, 0);
                a = __builtin_amdgcn_mfma_f32_16x16x32_bf16(al[kh], bh[k][kh], a, 0, 0, 0);
            }
            acc[k] = a;
        }
#pragma unroll
        for (int r = 0; r < 4; ++r) {
            const int vr = v0 + 16 * m + 4 * q + r;
            if (vr < Vv) {
                f32x4 o;
                o[0] = (acc[0][r] + bias4[0]) * scale4[0];
                o[1] = (acc[1][r] + bias4[1]) * scale4[1];
                o[2] = (acc[2][r] + bias4[2]) * scale4[2];
                o[3] = (acc[3][r] + bias4[3]) * scale4[3];
                *(f32x4*)(tab + (size_t)vr * 256 + (16 * w + mn) * 4) = o;
            }
        }
    }
}

// ---------------------------------------------------------------------------
// v11 recurrence == v8 (the verified 169.7us structure: 256 blocks x 4 rows,
// 4 waves, 1 unit/lane, in-register gates, token-register prefetch, 8-slot
// distance-4 S rotation, ONE novm-barrier/step) + prescaled activations
// (the only clean trim from v10): 4 dependent v_muls deleted from the
// gate->activation chain. Structural map after v9/v10 falsifications:
// v8 790 cyc/step < v10 dual-group 1253 < v9 wave-solo 1608. The cross-wave
// h-exchange (~310 cyc) is cheaper than every tested alternative.
// ---------------------------------------------------------------------------
__launch_bounds__(256, 1)
__global__ void lstm_main(const int*   __restrict__ s1,
                          const int*   __restrict__ s2,
                          const int*   __restrict__ len1,
                          const int*   __restrict__ len2,
                          const float* __restrict__ tab1,
                          const float* __restrict__ tab2,
                          const float* __restrict__ Whh1,
                          const float* __restrict__ Whh2,
                          const float* __restrict__ Wl1,
                          const float* __restrict__ bl1,
                          const float* __restrict__ Wl2,
                          const float* __restrict__ bl2,
                          float* __restrict__ out) {
    const int tid  = threadIdx.x;
    const int w    = tid >> 6;        // wave: unit tile [16w,16w+16)
    const int lane = tid & 63;
    const int q    = lane >> 4;       // MFMA quad
    const int mn   = lane & 15;       // B/C column
    const int row  = mn & 3;          // batch row within block
    const bool sb0 = (mn >> 2) & 1;   // rsel bit0
    const bool sb1 = (mn >> 3) & 1;   // rsel bit1
    const int u_own = 16 * w + 4 * q + (mn >> 2);  // this lane's hidden unit
    const int b0   = blockIdx.x * 4;

    __shared__ __align__(16) __bf16 hsh[2][4][96];  // row stride 192B: 2-way banks
    __shared__ __align__(16) int toklds[4][Tt + 8]; // per-row contiguous, padded
    __shared__ float h2s[4][64];
    __shared__ float ys[4][128];

    float c = 0.0f, selh = 0.0f, selc = 0.0f;
    const f32x4 zero4 = {0.0f, 0.0f, 0.0f, 0.0f};

    for (int phase = 0; phase < 2; ++phase) {
        const float* tab  = phase ? tab2 : tab1;
        const float* Whh  = phase ? Whh2 : Whh1;
        const int*   sent = phase ? s2 : s1;
        const int*   lenp = phase ? len2 : len1;

        // stage tokens per-row contiguous (coalesced over t; one-time)
        for (int i = tid; i < 4 * Tt; i += 256)
            toklds[i >> 8][i & 255] = sent[(size_t)(b0 + (i >> 8)) * Tt + (i & 255)];

        // A fragments, PRESCALED: m-tile k (gate type) covers gates 64k+16w+0..15
        b16x8 af[8];
#pragma unroll
        for (int k = 0; k < 4; ++k) {
            const int gate = 64 * k + 16 * w + mn;
            const float sck = (k == 2) ? -2.885390082f : -1.442695041f;
#pragma unroll
            for (int kh = 0; kh < 2; ++kh) {
                const float* ar = Whh + (size_t)gate * Hh + kh * 32 + q * 8;
                const float4 f0 = *(const float4*)ar;
                const float4 f1 = *(const float4*)(ar + 4);
                b16x8 a;
                a[0] = (__bf16)(f0.x * sck); a[1] = (__bf16)(f0.y * sck);
                a[2] = (__bf16)(f0.z * sck); a[3] = (__bf16)(f0.w * sck);
                a[4] = (__bf16)(f1.x * sck); a[5] = (__bf16)(f1.y * sck);
                a[6] = (__bf16)(f1.z * sck); a[7] = (__bf16)(f1.w * sck);
                af[2 * k + kh] = a;
            }
        }

        const int mi = lenp[(size_t)(b0 + row) * Hh + u_own];

        // seed h/c (zeros phase 0, gathered state phase 1) into buffer 0
        const float h0f = phase ? selh : 0.0f;
        c = phase ? selc : 0.0f;
        hsh[0][row][u_own] = (__bf16)h0f;
        selh = 0.0f; selc = 0.0f;
        __syncthreads();

        const float* tu = tab + 4 * u_own;

        // token register chunks: tkA = tokens[tb+4..7], tkB = tokens[tb+8..11]
        int4 tk0 = *(const int4*)&toklds[row][0];
        int4 tkA = *(const int4*)&toklds[row][4];
        int4 tkB = *(const int4*)&toklds[row][8];

        // prime S slots 0..3 (t=0..3); slots 4..7 are filled during steps 0..3
        f32x4 S0, S1, S2, S3, S4, S5, S6, S7;
        S0 = *(const f32x4*)(tu + (size_t)tk0.x * 256);
        S1 = *(const f32x4*)(tu + (size_t)tk0.y * 256);
        S2 = *(const f32x4*)(tu + (size_t)tk0.z * 256);
        S3 = *(const f32x4*)(tu + (size_t)tk0.w * 256);

        // select acc element rsel (2-bit, runtime) with static element indices
        auto pick = [&](const f32x4& a) -> float {
            const float e01 = sb0 ? a[1] : a[0];
            const float e23 = sb0 ? a[3] : a[2];
            return sb1 ? e23 : e01;
        };

        // step i: consume Su (slot i), refill Sf (slot (i+4)&7) with token tok
        auto step = [&](int i, f32x4& Su, f32x4& Sf, int tok, int tb) {
            // refill FIRST: register token -> address ready, no compute dep,
            // load issues at step start; consumed slot Su untouched.
            Sf = *(const f32x4*)(tu + (size_t)tok * 256);

            const int rb = i & 1, wb = rb ^ 1;
            const b16x8 bf0 = *(const b16x8*)&hsh[rb][row][q * 8];
            const b16x8 bf1 = *(const b16x8*)&hsh[rb][row][32 + q * 8];

            // order g,i,f,o: tanh(gG) is the longest dependent chain
            f32x4 aG = __builtin_amdgcn_mfma_f32_16x16x32_bf16(af[4], bf0, zero4, 0, 0, 0);
            aG = __builtin_amdgcn_mfma_f32_16x16x32_bf16(af[5], bf1, aG, 0, 0, 0);
            f32x4 aI = __builtin_amdgcn_mfma_f32_16x16x32_bf16(af[0], bf0, zero4, 0, 0, 0);
            aI = __builtin_amdgcn_mfma_f32_16x16x32_bf16(af[1], bf1, aI, 0, 0, 0);
            f32x4 aF = __builtin_amdgcn_mfma_f32_16x16x32_bf16(af[2], bf0, zero4, 0, 0, 0);
            aF = __builtin_amdgcn_mfma_f32_16x16x32_bf16(af[3], bf1, aF, 0, 0, 0);
            f32x4 aO = __builtin_amdgcn_mfma_f32_16x16x32_bf16(af[6], bf0, zero4, 0, 0, 0);
            aO = __builtin_amdgcn_mfma_f32_16x16x32_bf16(af[7], bf1, aO, 0, 0, 0);

            const float gG = pick(aG) + Su[2];
            const float gI = pick(aI) + Su[0];
            const float gF = pick(aF) + Su[1];
            const float gO = pick(aO) + Su[3];

            const float gv = ftanh_p(gG);
            const float iv = fsig_p(gI);
            const float fv = fsig_p(gF);
            const float ov = fsig_p(gO);
            c = fv * c + iv * gv;
            const float hv = ov * ftanh(c);
            hsh[wb][row][u_own] = (__bf16)hv;   // write first: off the tail
            if (tb + i == mi) { selh = hv; selc = c; }
            barrier_novm();   // ONE barrier/step; global prefetch stays in flight
        };

        for (int tb = 0; tb < Tt; tb += 8) {
            step(0, S0, S4, tkA.x, tb);
            step(1, S1, S5, tkA.y, tb);
            // next-iteration token chunks (ds_read latency hidden under steps)
            const int nb1 = min(tb + 12, Tt - 4);
            const int4 tA2 = *(const int4*)&toklds[row][nb1];
            step(2, S2, S6, tkA.z, tb);
            const int nb2 = min(tb + 16, Tt - 4);
            const int4 tB2 = *(const int4*)&toklds[row][nb2];
            step(3, S3, S7, tkA.w, tb);
            step(4, S4, S0, tkB.x, tb);
            step(5, S5, S1, tkB.y, tb);
            step(6, S6, S2, tkB.z, tb);
            step(7, S7, S3, tkB.w, tb);
            tkA = tA2; tkB = tB2;
        }
    }

    // ---------------- epilogue MLP on the 4 gathered rows -------------------
    h2s[row][u_own] = selh;
    __syncthreads();
#pragma unroll
    for (int p = 0; p < 2; ++p) {
        const int idx = tid + 256 * p;        // 512 (row, neuron) tasks
        const int rr = idx >> 7, n = idx & 127;
        float a = bl1[n];
        const float* wl = Wl1 + n * 64;
#pragma unroll 8
        for (int k = 0; k < 64; ++k) a += h2s[rr][k] * wl[k];
        ys[rr][n] = ftanh(a);
    }
    __syncthreads();
    if (tid < 16) {
        const int rr = tid >> 2, o = tid & 3;
        float a = bl2[o];
        const float* wl = Wl2 + o * 128;
#pragma unroll 8
        for (int k = 0; k < 128; ++k) a += ys[rr][k] * wl[k];
        out[(size_t)(b0 + rr) * 4 + o] = a;
    }
}

// ---------------------------------------------------------------------------
extern "C" void kernel_launch(void* const* d_in, const int* in_sizes, int n_in,
                              void* d_out, int out_size, void* d_ws, size_t ws_size,
                              hipStream_t stream) {
    const int*   s1   = (const int*)d_in[0];
    const int*   s2   = (const int*)d_in[1];
    const int*   l1   = (const int*)d_in[2];
    const int*   l2   = (const int*)d_in[3];
    // d_in[4], d_in[5] (s1_s, s2_s) unused by the reference
    const float* emb  = (const float*)d_in[6];
    const float* Wih1 = (const float*)d_in[7];
    const float* Whh1 = (const float*)d_in[8];
    const float* bih1 = (const float*)d_in[9];
    const float* bhh1 = (const float*)d_in[10];
    const float* Wih2 = (const float*)d_in[11];
    const float* Whh2 = (const float*)d_in[12];
    const float* bih2 = (const float*)d_in[13];
    const float* bhh2 = (const float*)d_in[14];
    const float* Wl1  = (const float*)d_in[15];
    const float* bl1  = (const float*)d_in[16];
    const float* Wl2  = (const float*)d_in[17];
    const float* bl2  = (const float*)d_in[18];
    float* out = (float*)d_out;

    float* tab1 = (float*)d_ws;                       // [V,256] fp32, unit-major
    float* tab2 = tab1 + (size_t)Vv * 256;            // [V,256] fp32  (65.6 MB)

    dim3 grid((Vv + MB - 1) / MB, 2);
    build_tables<<<grid, 256, 0, stream>>>(emb, Wih1, bih1, bhh1,
                                           Wih2, bih2, bhh2, tab1, tab2);
    lstm_main<<<Bsz / 4, 256, 0, stream>>>(s1, s2, l1, l2, tab1, tab2,
                                           Whh1, Whh2, Wl1, bl1, Wl2, bl2, out);
}